// Round 1
// baseline (75.236 us; speedup 1.0000x reference)
//
#include <hip/hip_runtime.h>

// labels[b,l,c] = argmin_q ( LN(t)[b,l,c] - LN(code_book)[c,q] )
//              = argmax_q LN(code_book)[c,q]        (tn constant along q)
//              = argmax_q code_book[c,q]            (global-scalar LN is monotone)
// => output is a 256-entry per-c label vector broadcast over (B, L).

#define C_DIM 256
#define Q_DIM 256
#define OUT_ELEMS (4 * 512 * 256)   // B * L * C = 524288

// One thread per codebook row: first-index argmax (strict >) reproduces
// jnp.argmin's first-min tie-breaking on (tn - cbn).
__global__ void argmax_rows(const float* __restrict__ cb, int* __restrict__ lab) {
    int c = threadIdx.x;  // 256 threads, 1 block
    const float* row = cb + c * Q_DIM;
    float best = row[0];
    int bi = 0;
#pragma unroll 8
    for (int q = 1; q < Q_DIM; ++q) {
        float v = row[q];
        if (v > best) { best = v; bi = q; }
    }
    lab[c] = bi;
}

// out[i] = lab[i % 256], int4-vectorized (4 int32 / 16B per lane).
__global__ void broadcast_labels(const int* __restrict__ lab, int* __restrict__ out) {
    __shared__ int s[C_DIM];
    s[threadIdx.x] = lab[threadIdx.x];
    __syncthreads();
    int i = blockIdx.x * blockDim.x + threadIdx.x;   // i indexes int4 groups
    int base = (i * 4) & (C_DIM - 1);                // multiple of 4, so base..base+3 stay in-row
    int4 v = make_int4(s[base], s[base + 1], s[base + 2], s[base + 3]);
    ((int4*)out)[i] = v;
}

extern "C" void kernel_launch(void* const* d_in, const int* in_sizes, int n_in,
                              void* d_out, int out_size, void* d_ws, size_t ws_size,
                              hipStream_t stream) {
    // inputs: 0=input_values (B,L,D) f32, 1=W (Q,D) f32, 2=code_book (C,Q) f32, 3=raw_signal int
    const float* code_book = (const float*)d_in[2];
    int* out = (int*)d_out;
    int* lab = (int*)d_ws;  // 256 * 4 B scratch

    argmax_rows<<<1, C_DIM, 0, stream>>>(code_book, lab);

    int n4 = OUT_ELEMS / 4;            // 131072 int4 stores
    broadcast_labels<<<n4 / C_DIM, C_DIM, 0, stream>>>(lab, out);
}